// Round 6
// baseline (1725.892 us; speedup 1.0000x reference)
//
#include <hip/hip_runtime.h>
#include <hip/hip_bf16.h>

constexpr int N = 10000;   // nodes
constexpr int D = 512;     // feature dim
constexpr int E = 160000;  // edges
constexpr float EPS = 1e-5f;
constexpr int NBLK = 512;              // co-resident blocks (2 per CU guaranteed)
constexpr int NTHR = NBLK * 256;

typedef _Float16 half8 __attribute__((ext_vector_type(8)));
typedef _Float16 half2v __attribute__((ext_vector_type(2)));
typedef float floatx4 __attribute__((ext_vector_type(4)));

// async global->LDS, 16B per lane. LDS dest = wave-uniform base + lane*16.
__device__ __forceinline__ void glds16(const _Float16* g, _Float16* l) {
    __builtin_amdgcn_global_load_lds(
        (const __attribute__((address_space(1))) uint32_t*)(g),
        (__attribute__((address_space(3))) uint32_t*)(l),
        16, 0, 0);
}

// Grid barrier: generation counter, device(agent)-scope atomics.
// ACQ_REL arrival gives release (L2 writeback); ACQUIRE poll/passing gives
// invalidate -> normal loads after the barrier see other XCDs' stores.
__device__ __forceinline__ void gbar(int* cnt, volatile int* gen, int target) {
    __syncthreads();
    if (threadIdx.x == 0) {
        int arrived = __hip_atomic_fetch_add(cnt, 1, __ATOMIC_ACQ_REL,
                                             __HIP_MEMORY_SCOPE_AGENT) + 1;
        if (arrived == NBLK) {
            __hip_atomic_store(cnt, 0, __ATOMIC_RELAXED, __HIP_MEMORY_SCOPE_AGENT);
            __hip_atomic_store((int*)gen, target, __ATOMIC_RELEASE,
                               __HIP_MEMORY_SCOPE_AGENT);
        } else {
            while (__hip_atomic_load((int*)gen, __ATOMIC_ACQUIRE,
                                     __HIP_MEMORY_SCOPE_AGENT) < target)
                __builtin_amdgcn_s_sleep(16);
        }
    }
    __syncthreads();
}

// ---------------------------------------------------------------------------
// The whole pipeline in one persistent kernel.
// ---------------------------------------------------------------------------
__global__ __launch_bounds__(256, 2) void mono(
    const float* __restrict__ x_in, const int* __restrict__ src,
    const int* __restrict__ dst, const float* __restrict__ gamma,
    const float* __restrict__ beta, const float* __restrict__ W,
    const float* __restrict__ bias, float* __restrict__ out,
    _Float16* __restrict__ x16a, _Float16* __restrict__ x16b,
    _Float16* __restrict__ aggb, _Float16* __restrict__ Wt,
    float* __restrict__ src_norm, float* __restrict__ dst_norm,
    int* __restrict__ out_deg, int* __restrict__ in_deg,
    float* __restrict__ stats0, float* __restrict__ stats1,
    float* __restrict__ stats2,
    int* __restrict__ csr_off, int* __restrict__ cursor,
    int* __restrict__ csr_src, int* bar_cnt, int* bar_gen) {

    const int tid  = threadIdx.x;
    const int bid  = blockIdx.x;
    const int gid  = bid * 256 + tid;
    const int wave = tid >> 6;
    const int lane = tid & 63;
    const int quad = lane >> 4;
    const int l16  = lane & 15;

    __shared__ __align__(16) char smem[12288];  // union: mm As+Bs / transpose / scan

    // ================= S0a: degrees =================
    for (int e = gid; e < E; e += NTHR) {
        atomicAdd(&out_deg[src[e]], 1);
        atomicAdd(&in_deg[dst[e]], 1);
    }
    // ================= S0b: x fp32->f16 + column stats =================
    {
        int c2 = tid * 2;
        float s0 = 0.f, s1 = 0.f, q0 = 0.f, q1 = 0.f;
        for (int r = bid; r < N; r += NBLK) {
            float2 v = *(const float2*)(x_in + (size_t)r * D + c2);
            s0 += v.x; q0 += v.x * v.x;
            s1 += v.y; q1 += v.y * v.y;
            half2v h; h[0] = (_Float16)v.x; h[1] = (_Float16)v.y;
            *(half2v*)(x16a + (size_t)r * D + c2) = h;
        }
        atomicAdd(&stats0[c2], s0);
        atomicAdd(&stats0[c2 + 1], s1);
        atomicAdd(&stats0[D + c2], q0);
        atomicAdd(&stats0[D + c2 + 1], q1);
    }
    // ================= S0c: W transpose (768 32x32 tiles) =================
    {
        float (*tb)[33] = (float(*)[33])smem;
        int tx = tid & 31, ty = tid >> 5;
        for (int t = bid; t < 768; t += NBLK) {
            int l  = t >> 8;
            int tt = t & 255;
            int k0 = (tt >> 4) * 32, n0 = (tt & 15) * 32;
            const float* Wl = W + (size_t)l * D * D;
            _Float16* Wtl = Wt + (size_t)l * D * D;
            __syncthreads();
            for (int i = 0; i < 32; i += 8)
                tb[ty + i][tx] = Wl[(size_t)(k0 + ty + i) * D + n0 + tx];
            __syncthreads();
            for (int i = 0; i < 32; i += 8)
                Wtl[(size_t)(n0 + ty + i) * D + k0 + tx] = (_Float16)tb[tx][ty + i];
        }
    }
    gbar(bar_cnt, bar_gen, 1);

    // ================= S1: scan (block 0 only) =================
    if (bid == 0) {
        int* lsum = (int*)smem;
        const int chunk = (N + 255) / 256;  // 40
        int start = tid * chunk;
        int end = start + chunk; if (end > N) end = N;
        int s = 0;
        for (int i = start; i < end; ++i) s += in_deg[i];
        lsum[tid] = s;
        __syncthreads();
        for (int d = 1; d < 256; d <<= 1) {
            int v = (tid >= d) ? lsum[tid - d] : 0;
            __syncthreads();
            lsum[tid] += v;
            __syncthreads();
        }
        int excl = (tid == 0) ? 0 : lsum[tid - 1];
        for (int i = start; i < end; ++i) {
            csr_off[i] = excl;
            cursor[i] = excl;
            excl += in_deg[i];
            int od = out_deg[i]; if (od < 1) od = 1;
            int id = in_deg[i];  if (id < 1) id = 1;
            src_norm[i] = rsqrtf((float)od);
            dst_norm[i] = rsqrtf((float)id);
        }
        if (tid == 255) csr_off[N] = lsum[255];
    }
    gbar(bar_cnt, bar_gen, 2);

    // ================= S2: CSR fill =================
    for (int e = gid; e < E; e += NTHR) {
        int d_ = dst[e];
        int pos = atomicAdd(&cursor[d_], 1);
        csr_src[pos] = src[e];
    }
    gbar(bar_cnt, bar_gen, 3);

    // ================= layers =================
    #pragma unroll 1
    for (int l = 0; l < 3; ++l) {
        const _Float16* xcur = (l == 1) ? x16b : x16a;
        _Float16* xnext      = (l == 0) ? x16b : x16a;   // used for l<2
        const float* st_in   = (l == 0) ? stats0 : ((l == 1) ? stats1 : stats2);
        float* st_out        = (l == 0) ? stats1 : stats2;  // used for l<2
        const float* gl = gamma + l * D;
        const float* bl = beta + l * D;
        const _Float16* Bt = Wt + (size_t)l * D * D;
        const float* bi = bias + l * D;

        // ---- S3: fused BN + gather-aggregate -> aggb (wave per node) ----
        {
            int c0 = lane * 8;
            float scale[8], shift[8];
            const float invN = 1.0f / (float)N;
            for (int i = 0; i < 8; ++i) {
                int c = c0 + i;
                float mu = st_in[c] * invN;
                float var = st_in[D + c] * invN - mu * mu;
                float sc = gl[c] * rsqrtf(var + EPS);
                scale[i] = sc;
                shift[i] = bl[c] - mu * sc;
            }
            for (int n = bid * 4 + wave; n < N; n += NBLK * 4) {
                int e0 = csr_off[n], e1 = csr_off[n + 1];
                float a[8] = {}, a2[8] = {};
                float t = 0.f;
                int e = e0;
                for (; e + 2 <= e1; e += 2) {
                    int s0 = csr_src[e];
                    int s1 = csr_src[e + 1];
                    float n0 = src_norm[s0];
                    float n1 = src_norm[s1];
                    half8 v0 = *(const half8*)(xcur + (size_t)s0 * D + c0);
                    half8 v1 = *(const half8*)(xcur + (size_t)s1 * D + c0);
                    t += n0 + n1;
                    for (int k = 0; k < 8; ++k) {
                        a[k]  += (float)v0[k] * n0;
                        a2[k] += (float)v1[k] * n1;
                    }
                }
                if (e < e1) {
                    int s0 = csr_src[e];
                    float n0 = src_norm[s0];
                    half8 v0 = *(const half8*)(xcur + (size_t)s0 * D + c0);
                    t += n0;
                    for (int k = 0; k < 8; ++k) a[k] += (float)v0[k] * n0;
                }
                float dn = dst_norm[n];
                half8 o;
                for (int k = 0; k < 8; ++k)
                    o[k] = (_Float16)(dn * (scale[k] * (a[k] + a2[k]) + shift[k] * t));
                *(half8*)(aggb + (size_t)n * D + c0) = o;
            }
        }
        gbar(bar_cnt, bar_gen, 4 + 2 * l);

        // ---- S4: mm over 79x8 = 632 tiles of 128x64, LDS-staged ----
        {
            _Float16* As = (_Float16*)smem;            // 128*32 f16 = 8 KB
            _Float16* Bs = (_Float16*)(smem + 8192);   // 64*32 f16 = 4 KB
            const int sr = lane >> 2;
            const int sc = (lane & 3) * 8;
            const int wm = (wave & 1) * 64;
            const int wn = (wave >> 1) * 32;
            for (int t = bid; t < 632; t += NBLK) {
                int row0 = (t % 79) * 128;
                int col0 = (t / 79) * 64;
                int ar0 = row0 + wave * 32 + sr;
                int ar1 = ar0 + 16;
                if (ar0 >= N) ar0 = N - 1;
                if (ar1 >= N) ar1 = N - 1;
                const _Float16* gA0 = aggb + (size_t)ar0 * D + sc;
                const _Float16* gA1 = aggb + (size_t)ar1 * D + sc;
                const _Float16* gB  = Bt + (size_t)(col0 + wave * 16 + sr) * D + sc;
                _Float16* lA0 = As + (wave * 32) * 32;
                _Float16* lA1 = As + (wave * 32 + 16) * 32;
                _Float16* lB  = Bs + (wave * 16) * 32;
                floatx4 acc[4][2] = {};
                for (int k0 = 0; k0 < D; k0 += 32) {
                    __syncthreads();
                    glds16(gA0 + k0, lA0);
                    glds16(gA1 + k0, lA1);
                    glds16(gB + k0, lB);
                    __syncthreads();
                    half8 af[4], bf[2];
                    for (int i = 0; i < 4; ++i)
                        af[i] = *(const half8*)(As + (wm + i * 16 + l16) * 32 + quad * 8);
                    for (int j = 0; j < 2; ++j)
                        bf[j] = *(const half8*)(Bs + (wn + j * 16 + l16) * 32 + quad * 8);
                    for (int i = 0; i < 4; ++i)
                        for (int j = 0; j < 2; ++j)
                            acc[i][j] = __builtin_amdgcn_mfma_f32_16x16x32_f16(
                                af[i], bf[j], acc[i][j], 0, 0, 0);
                }
                // epilogue: C/D layout col = lane&15, row = quad*4 + reg
                float s[2] = {}, q[2] = {};
                for (int i = 0; i < 4; ++i) {
                    for (int r = 0; r < 4; ++r) {
                        int row = row0 + wm + i * 16 + quad * 4 + r;
                        bool valid = row < N;
                        for (int j = 0; j < 2; ++j) {
                            int col = col0 + wn + j * 16 + l16;
                            float v = acc[i][j][r] + bi[col];
                            v = v > 0.f ? v : 0.f;
                            if (valid) {
                                if (l == 2) out[(size_t)row * D + col] = v;
                                else xnext[(size_t)row * D + col] = (_Float16)v;
                                s[j] += v; q[j] += v * v;
                            }
                        }
                    }
                }
                if (l < 2) {
                    for (int j = 0; j < 2; ++j) {
                        float sv = s[j], qv = q[j];
                        sv += __shfl_xor(sv, 16); sv += __shfl_xor(sv, 32);
                        qv += __shfl_xor(qv, 16); qv += __shfl_xor(qv, 32);
                        if (quad == 0) {
                            int col = col0 + wn + j * 16 + l16;
                            atomicAdd(&st_out[col], sv);
                            atomicAdd(&st_out[D + col], qv);
                        }
                    }
                }
            }
        }
        if (l < 2) gbar(bar_cnt, bar_gen, 5 + 2 * l);
    }
}

// ---------------------------------------------------------------------------
extern "C" void kernel_launch(void* const* d_in, const int* in_sizes, int n_in,
                              void* d_out, int out_size, void* d_ws, size_t ws_size,
                              hipStream_t stream) {
    const float* x_in  = (const float*)d_in[0];
    const int*   src   = (const int*)d_in[1];
    const int*   dst   = (const int*)d_in[2];
    const float* gamma = (const float*)d_in[3];
    const float* beta  = (const float*)d_in[4];
    const float* W     = (const float*)d_in[5];
    const float* b     = (const float*)d_in[6];
    float* out = (float*)d_out;

    // workspace carve-up (16B-aligned segments first)
    char* p = (char*)d_ws;
    _Float16* x16a = (_Float16*)p; p += (size_t)N * D * 2;       // 10.24 MB
    _Float16* x16b = (_Float16*)p; p += (size_t)N * D * 2;       // 10.24 MB
    _Float16* aggb = (_Float16*)p; p += (size_t)N * D * 2;       // 10.24 MB
    _Float16* Wt   = (_Float16*)p; p += (size_t)3 * D * D * 2;   // 1.57 MB
    float* src_norm = (float*)p;   p += (size_t)N * 4;
    float* dst_norm = (float*)p;   p += (size_t)N * 4;
    // contiguous zero-init region: out_deg, in_deg, stats0..2, barrier
    int* out_deg   = (int*)p;      p += (size_t)N * 4;
    int* in_deg    = (int*)p;      p += (size_t)N * 4;
    float* stats0  = (float*)p;    p += 2 * D * 4;
    float* stats1  = (float*)p;    p += 2 * D * 4;
    float* stats2  = (float*)p;    p += 2 * D * 4;
    int* bar_cnt   = (int*)p;      p += 16;   // padded
    int* bar_gen   = (int*)p;      p += 16;
    size_t zero_bytes = (char*)p - (char*)out_deg;
    int* csr_off   = (int*)p;      p += (size_t)(N + 1) * 4;
    int* cursor    = (int*)p;      p += (size_t)N * 4;
    int* csr_src   = (int*)p;      p += (size_t)E * 4;

    hipMemsetAsync(out_deg, 0, zero_bytes, stream);
    mono<<<NBLK, 256, 0, stream>>>(
        x_in, src, dst, gamma, beta, W, b, out,
        x16a, x16b, aggb, Wt, src_norm, dst_norm,
        out_deg, in_deg, stats0, stats1, stats2,
        csr_off, cursor, csr_src, bar_cnt, bar_gen);
}

// Round 7
// 281.389 us; speedup vs baseline: 6.1335x; 6.1335x over previous
//
#include <hip/hip_runtime.h>
#include <hip/hip_bf16.h>

constexpr int N = 10000;   // nodes
constexpr int D = 512;     // feature dim
constexpr int E = 160000;  // edges
constexpr int L = 3;       // layers
constexpr float EPS = 1e-5f;

typedef _Float16 half8 __attribute__((ext_vector_type(8)));
typedef _Float16 half2v __attribute__((ext_vector_type(2)));
typedef float floatx4 __attribute__((ext_vector_type(4)));

// async global->LDS, 16B per lane. LDS dest = wave-uniform base + lane*16.
__device__ __forceinline__ void glds16(const _Float16* g, _Float16* l) {
    __builtin_amdgcn_global_load_lds(
        (const __attribute__((address_space(1))) uint32_t*)(g),
        (__attribute__((address_space(3))) uint32_t*)(l),
        16, 0, 0);
}

// ---------------------------------------------------------------------------
// Mega setup: degrees + x fp32->f16 conversion + column stats + W transpose.
// Roles by blockIdx.x.
// ---------------------------------------------------------------------------
constexpr int DEG_BLOCKS  = (E + 255) / 256;   // 625
constexpr int CONV_BLOCKS = 100;               // 100 rows each
constexpr int TW_BLOCKS   = L * 256;           // 768 (32x32 tiles)
constexpr int MEGA_BLOCKS = DEG_BLOCKS + CONV_BLOCKS + TW_BLOCKS;

__global__ __launch_bounds__(256) void mega_setup(
    const int* __restrict__ src, const int* __restrict__ dst,
    const float* __restrict__ x, const float* __restrict__ W,
    int* __restrict__ out_deg, int* __restrict__ in_deg,
    _Float16* __restrict__ x16, float* __restrict__ stats0,
    _Float16* __restrict__ Wt) {
    __shared__ float tb[32][33];
    int bid = blockIdx.x;
    int tid = threadIdx.x;
    if (bid < DEG_BLOCKS) {
        int e = bid * 256 + tid;
        if (e < E) {
            atomicAdd(&out_deg[src[e]], 1);
            atomicAdd(&in_deg[dst[e]], 1);
        }
    } else if (bid < DEG_BLOCKS + CONV_BLOCKS) {
        int b = bid - DEG_BLOCKS;
        int r0 = b * 100;
        int r1 = r0 + 100; if (r1 > N) r1 = N;
        int c2 = tid * 2;
        float s0 = 0.f, s1 = 0.f, q0 = 0.f, q1 = 0.f;
        for (int r = r0; r < r1; ++r) {
            float2 v = *(const float2*)(x + (size_t)r * D + c2);
            s0 += v.x; q0 += v.x * v.x;
            s1 += v.y; q1 += v.y * v.y;
            half2v h; h[0] = (_Float16)v.x; h[1] = (_Float16)v.y;
            *(half2v*)(x16 + (size_t)r * D + c2) = h;
        }
        atomicAdd(&stats0[c2], s0);
        atomicAdd(&stats0[c2 + 1], s1);
        atomicAdd(&stats0[D + c2], q0);
        atomicAdd(&stats0[D + c2 + 1], q1);
    } else {
        int b = bid - DEG_BLOCKS - CONV_BLOCKS;  // 0..767
        int l = b >> 8;
        int t = b & 255;
        int k0 = (t >> 4) * 32, n0 = (t & 15) * 32;
        int tx = tid & 31, ty = tid >> 5;  // 32 x 8
        const float* Wl = W + (size_t)l * D * D;
        _Float16* Wtl = Wt + (size_t)l * D * D;
        for (int i = 0; i < 32; i += 8)
            tb[ty + i][tx] = Wl[(size_t)(k0 + ty + i) * D + n0 + tx];
        __syncthreads();
        for (int i = 0; i < 32; i += 8)
            Wtl[(size_t)(n0 + ty + i) * D + k0 + tx] = (_Float16)tb[tx][ty + i];
    }
}

// ---------------------------------------------------------------------------
// Single block: exclusive scan of in_deg -> off & cursor, plus both norms.
// ---------------------------------------------------------------------------
__global__ void scan_indeg(const int* __restrict__ in_deg,
                           const int* __restrict__ out_deg,
                           int* __restrict__ off, int* __restrict__ cursor,
                           float* __restrict__ src_norm, float* __restrict__ dst_norm) {
    __shared__ int lsum[1024];
    int t = threadIdx.x;
    const int chunk = (N + 1023) / 1024;
    int start = t * chunk;
    int end = start + chunk; if (end > N) end = N;
    int s = 0;
    for (int i = start; i < end; ++i) s += in_deg[i];
    lsum[t] = s;
    __syncthreads();
    for (int d = 1; d < 1024; d <<= 1) {
        int v = (t >= d) ? lsum[t - d] : 0;
        __syncthreads();
        lsum[t] += v;
        __syncthreads();
    }
    int excl = (t == 0) ? 0 : lsum[t - 1];
    for (int i = start; i < end; ++i) {
        off[i] = excl;
        cursor[i] = excl;
        excl += in_deg[i];
        int od = out_deg[i]; if (od < 1) od = 1;
        int id = in_deg[i];  if (id < 1) id = 1;
        src_norm[i] = rsqrtf((float)od);
        dst_norm[i] = rsqrtf((float)id);
    }
    if (t == 1023) off[N] = lsum[1023];
}

__global__ void csr_fill(const int* __restrict__ src, const int* __restrict__ dst,
                         int* __restrict__ cursor, int* __restrict__ csr_src) {
    int e = blockIdx.x * blockDim.x + threadIdx.x;
    if (e >= E) return;
    int d = dst[e];
    int pos = atomicAdd(&cursor[d], 1);
    csr_src[pos] = src[e];
}

// ---------------------------------------------------------------------------
// Fused BN + gather-aggregate, coef in-register from stats. One wave per node.
// 4x edge unroll: 4 independent 1KB row loads in flight per iteration.
// ---------------------------------------------------------------------------
__global__ __launch_bounds__(256) void aggregate_bn(
    const _Float16* __restrict__ x, const int* __restrict__ off,
    const int* __restrict__ csr_src, const float* __restrict__ src_norm,
    const float* __restrict__ dst_norm, const float* __restrict__ stats,
    const float* __restrict__ gamma, const float* __restrict__ beta,
    _Float16* __restrict__ agg) {
    int wid = (blockIdx.x * 256 + threadIdx.x) >> 6;
    if (wid >= N) return;
    int lane = threadIdx.x & 63;
    int c0 = lane * 8;

    float scale[8], shift[8];
    const float invN = 1.0f / (float)N;
    for (int i = 0; i < 8; ++i) {
        int c = c0 + i;
        float mu = stats[c] * invN;
        float var = stats[D + c] * invN - mu * mu;
        float sc = gamma[c] * rsqrtf(var + EPS);
        scale[i] = sc;
        shift[i] = beta[c] - mu * sc;
    }

    int e0 = off[wid], e1 = off[wid + 1];
    float a[8] = {}, a2[8] = {};
    float t = 0.f;
    int e = e0;
    for (; e + 4 <= e1; e += 4) {
        int s0 = csr_src[e];
        int s1 = csr_src[e + 1];
        int s2 = csr_src[e + 2];
        int s3 = csr_src[e + 3];
        float n0 = src_norm[s0];
        float n1 = src_norm[s1];
        float n2 = src_norm[s2];
        float n3 = src_norm[s3];
        half8 v0 = *(const half8*)(x + (size_t)s0 * D + c0);
        half8 v1 = *(const half8*)(x + (size_t)s1 * D + c0);
        half8 v2 = *(const half8*)(x + (size_t)s2 * D + c0);
        half8 v3 = *(const half8*)(x + (size_t)s3 * D + c0);
        t += (n0 + n1) + (n2 + n3);
        for (int k = 0; k < 8; ++k) {
            a[k]  += (float)v0[k] * n0;
            a2[k] += (float)v1[k] * n1;
            a[k]  += (float)v2[k] * n2;
            a2[k] += (float)v3[k] * n3;
        }
    }
    for (; e < e1; ++e) {
        int s0 = csr_src[e];
        float n0 = src_norm[s0];
        half8 v0 = *(const half8*)(x + (size_t)s0 * D + c0);
        t += n0;
        for (int k = 0; k < 8; ++k) a[k] += (float)v0[k] * n0;
    }
    float dn = dst_norm[wid];
    half8 o;
    for (int i = 0; i < 8; ++i)
        o[i] = (_Float16)(dn * (scale[i] * (a[i] + a2[i]) + shift[i] * t));
    *(half8*)(agg + (size_t)wid * D + c0) = o;
}

// ---------------------------------------------------------------------------
// C = relu(A @ W + bias) via f16 MFMA with global_load_lds staging.
// A: M x 512 f16.  Bt[n][k] = W[k][n] f16.
// Block 256 = 4 waves; tile 128(M) x 128(N); BK=32.
// Wave computes 64x64 (4x4 tiles of mfma_f32_16x16x32_f16).
// ---------------------------------------------------------------------------
template <typename OutT, bool STATS>
__global__ __launch_bounds__(256) void mm_f16_relu(
    const _Float16* __restrict__ A, const _Float16* __restrict__ Bt,
    const float* __restrict__ bias, OutT* __restrict__ C, int M,
    float* __restrict__ stats) {
    __shared__ __align__(16) _Float16 As[128 * 32];
    __shared__ __align__(16) _Float16 Bs[128 * 32];
    const int tid  = threadIdx.x;
    const int wave = tid >> 6;
    const int lane = tid & 63;
    const int quad = lane >> 4;
    const int l16  = lane & 15;
    const int row0 = blockIdx.x * 128;
    const int col0 = blockIdx.y * 128;
    const int wm = (wave & 1) * 64;
    const int wn = (wave >> 1) * 64;
    const int sr = lane >> 2;
    const int sc = (lane & 3) * 8;

    // staging: wave w loads A rows [w*32, w*32+32) and B rows [w*32, w*32+32)
    // (two 16-row slabs each). Per-lane global ptr, wave-uniform LDS base.
    int ar0 = row0 + wave * 32 + sr;
    int ar1 = ar0 + 16;
    if (ar0 >= M) ar0 = M - 1;
    if (ar1 >= M) ar1 = M - 1;
    const _Float16* gA0 = A + (size_t)ar0 * D + sc;
    const _Float16* gA1 = A + (size_t)ar1 * D + sc;
    const _Float16* gB0 = Bt + (size_t)(col0 + wave * 32 + sr) * D + sc;
    const _Float16* gB1 = Bt + (size_t)(col0 + wave * 32 + 16 + sr) * D + sc;
    _Float16* lA0 = As + (wave * 32) * 32;
    _Float16* lA1 = As + (wave * 32 + 16) * 32;
    _Float16* lB0 = Bs + (wave * 32) * 32;
    _Float16* lB1 = Bs + (wave * 32 + 16) * 32;

    floatx4 acc[4][4] = {};

    for (int k0 = 0; k0 < D; k0 += 32) {
        __syncthreads();
        glds16(gA0 + k0, lA0);
        glds16(gA1 + k0, lA1);
        glds16(gB0 + k0, lB0);
        glds16(gB1 + k0, lB1);
        __syncthreads();  // compiler inserts vmcnt(0) drain here
        half8 af[4], bf[4];
        for (int i = 0; i < 4; ++i)
            af[i] = *(const half8*)(As + (wm + i * 16 + l16) * 32 + quad * 8);
        for (int j = 0; j < 4; ++j)
            bf[j] = *(const half8*)(Bs + (wn + j * 16 + l16) * 32 + quad * 8);
        for (int i = 0; i < 4; ++i)
            for (int j = 0; j < 4; ++j)
                acc[i][j] = __builtin_amdgcn_mfma_f32_16x16x32_f16(
                    af[i], bf[j], acc[i][j], 0, 0, 0);
    }

    // epilogue: C/D layout col = lane&15, row = quad*4 + reg
    float s[4] = {}, q[4] = {};
    for (int i = 0; i < 4; ++i) {
        for (int r = 0; r < 4; ++r) {
            int row = row0 + wm + i * 16 + quad * 4 + r;
            bool valid = row < M;
            for (int j = 0; j < 4; ++j) {
                int col = col0 + wn + j * 16 + l16;
                float v = acc[i][j][r] + bias[col];
                v = v > 0.f ? v : 0.f;
                if (valid) {
                    C[(size_t)row * D + col] = (OutT)v;
                    if (STATS) { s[j] += v; q[j] += v * v; }
                }
            }
        }
    }
    if (STATS) {
        for (int j = 0; j < 4; ++j) {
            float sv = s[j], qv = q[j];
            sv += __shfl_xor(sv, 16); sv += __shfl_xor(sv, 32);
            qv += __shfl_xor(qv, 16); qv += __shfl_xor(qv, 32);
            if (quad == 0) {
                int col = col0 + wn + j * 16 + l16;
                atomicAdd(&stats[col], sv);
                atomicAdd(&stats[D + col], qv);
            }
        }
    }
}

// ---------------------------------------------------------------------------
extern "C" void kernel_launch(void* const* d_in, const int* in_sizes, int n_in,
                              void* d_out, int out_size, void* d_ws, size_t ws_size,
                              hipStream_t stream) {
    const float* x_in  = (const float*)d_in[0];
    const int*   src   = (const int*)d_in[1];
    const int*   dst   = (const int*)d_in[2];
    const float* gamma = (const float*)d_in[3];
    const float* beta  = (const float*)d_in[4];
    const float* W     = (const float*)d_in[5];
    const float* b     = (const float*)d_in[6];
    float* out = (float*)d_out;

    // workspace carve-up (16B-aligned segments first)
    char* p = (char*)d_ws;
    _Float16* x16 = (_Float16*)p;  p += (size_t)N * D * 2;       // 10.24 MB
    _Float16* agg = (_Float16*)p;  p += (size_t)N * D * 2;       // 10.24 MB
    _Float16* Wt  = (_Float16*)p;  p += (size_t)L * D * D * 2;   // 1.57 MB
    float* src_norm = (float*)p;   p += (size_t)N * 4;
    float* dst_norm = (float*)p;   p += (size_t)N * 4;
    // contiguous zero-init region: out_deg, in_deg, stats0..2
    int* out_deg   = (int*)p;      p += (size_t)N * 4;
    int* in_deg    = (int*)p;      p += (size_t)N * 4;
    float* stats0  = (float*)p;    p += 2 * D * 4;
    float* stats1  = (float*)p;    p += 2 * D * 4;
    float* stats2  = (float*)p;    p += 2 * D * 4;
    int* csr_off   = (int*)p;      p += (size_t)(N + 1) * 4;
    int* cursor    = (int*)p;      p += (size_t)N * 4;
    int* csr_src   = (int*)p;      p += (size_t)E * 4;

    float* stats_in[3] = {stats0, stats1, stats2};

    // --- setup ---
    hipMemsetAsync(out_deg, 0, (2 * (size_t)N + 6 * D) * sizeof(int), stream);
    mega_setup<<<MEGA_BLOCKS, 256, 0, stream>>>(src, dst, x_in, W,
                                                out_deg, in_deg, x16, stats0, Wt);
    scan_indeg<<<1, 1024, 0, stream>>>(in_deg, out_deg, csr_off, cursor,
                                       src_norm, dst_norm);
    csr_fill<<<DEG_BLOCKS, 256, 0, stream>>>(src, dst, cursor, csr_src);

    dim3 mm_grid((N + 127) / 128, D / 128);
    const int agg_blocks = (N + 3) / 4;  // 4 waves per 256-thread block

    for (int l = 0; l < L; ++l) {
        const float* gl  = gamma + (size_t)l * D;
        const float* bl  = beta + (size_t)l * D;
        const _Float16* Wl = Wt + (size_t)l * D * D;
        const float* bil = b + (size_t)l * D;

        aggregate_bn<<<agg_blocks, 256, 0, stream>>>(
            x16, csr_off, csr_src, src_norm, dst_norm, stats_in[l], gl, bl, agg);
        if (l == L - 1) {
            mm_f16_relu<float, false><<<mm_grid, 256, 0, stream>>>(
                agg, Wl, bil, out, N, nullptr);
        } else {
            mm_f16_relu<_Float16, true><<<mm_grid, 256, 0, stream>>>(
                agg, Wl, bil, x16, N, stats_in[l + 1]);
        }
    }
}